// Round 3
// baseline (579.835 us; speedup 1.0000x reference)
//
#include <hip/hip_runtime.h>
#include <hip/hip_cooperative_groups.h>
#include <math.h>

namespace cg = cooperative_groups;

#define BB 16
#define SS 512
#define DD 128
#define HH 8
#define NN (BB*SS)   // 8192 rows
#define LN_EPS 1e-5f

typedef __attribute__((ext_vector_type(8))) short short8;
typedef __attribute__((ext_vector_type(4))) short short4v;
typedef __attribute__((ext_vector_type(4))) float f4;

static __device__ __forceinline__ ushort f2bf(float x) {
  union { float f; unsigned u; } v; v.f = x;
  unsigned r = v.u + 0x7fffu + ((v.u >> 16) & 1u);
  return (ushort)(r >> 16);
}

static __device__ __forceinline__ float posenc(int s, int col) {
  const float inc = 0.14619588f;               // log(10000)/63
  int c = col & 63;
  float invf = expf(-inc * (float)c);
  float st = (float)s * invf;
  return (col < 64) ? sinf(st) : cosf(st);
}

// stage a 128x128 bf16 weight matrix into LDS (stride 152)
static __device__ __forceinline__ void stage_w(ushort* wbuf, const ushort* W, int t) {
  for (int i = t; i < 2048; i += 256) {
    int row = i >> 4, ch = i & 15;
    *(short8*)&wbuf[row*152 + ch*8] = *(const short8*)&W[row*128 + ch*8];
  }
}

// 16x128 @ 128x128 MFMA tile: A in abuf (stride 152), B rows in wbuf (stride 152)
static __device__ __forceinline__ void mm_tile(const ushort* abuf, const ushort* wbuf,
                                               int m, int qd, int c0, f4& acc0, f4& acc1) {
  #pragma unroll
  for (int ks = 0; ks < 4; ++ks) {
    short8 a  = *(const short8*)&abuf[m*152 + ks*32 + qd*8];
    short8 b0 = *(const short8*)&wbuf[(c0 + m)*152 + ks*32 + qd*8];
    short8 b1 = *(const short8*)&wbuf[(c0 + 16 + m)*152 + ks*32 + qd*8];
    acc0 = __builtin_amdgcn_mfma_f32_16x16x32_bf16(a, b0, acc0, 0, 0, 0);
    acc1 = __builtin_amdgcn_mfma_f32_16x16x32_bf16(a, b1, acc1, 0, 0, 0);
  }
}

// LN 16 rows of `in` (fp32, generic ptr) starting at row r0 -> abuf bf16 (stride 152)
static __device__ __forceinline__ void ln_rows_to_abuf(const float* in, int r0,
    const float* gamma, const float* beta, ushort* abuf, int wv, int lane) {
  for (int i = wv; i < 16; i += 4) {
    float2 xv = *(const float2*)&in[(size_t)(r0 + i)*128 + lane*2];
    float s1 = xv.x + xv.y, s2 = xv.x*xv.x + xv.y*xv.y;
    #pragma unroll
    for (int o = 32; o > 0; o >>= 1) { s1 += __shfl_xor(s1, o); s2 += __shfl_xor(s2, o); }
    float mu  = s1 * (1.0f/128.0f);
    float var = s2 * (1.0f/128.0f) - mu*mu;
    float inv = rsqrtf(var + LN_EPS);
    float2 gv = *(const float2*)&gamma[lane*2];
    float2 bv = *(const float2*)&beta[lane*2];
    float n0 = (xv.x - mu)*inv*gv.x + bv.x;
    float n1 = (xv.y - mu)*inv*gv.y + bv.y;
    unsigned pk = (unsigned)f2bf(n0) | ((unsigned)f2bf(n1) << 16);
    *(unsigned*)&abuf[i*152 + lane*2] = pk;
  }
}

struct MegaParams {
  const float* x; const int* mask;
  const float* ln_scale; const float* ln_bias;
  const float* dw_w; const float* dw_b; const float* pw_w; const float* pw_b;
  const float* Wq; const float* Wk; const float* Wv; const float* Wo;
  const float* att_bias; const float* f1_w; const float* f1_b;
  const float* f2_w; const float* f2_b;
  float* out;
  ushort* wbf; float* bufA; float* bufB; ushort* qkvbuf; ushort* attbuf;
};

// ---------------- conv layer: LN(+pos) + dwconv k=7 + pointwise MFMA + relu + residual ----------------
static __device__ void conv_stage(unsigned char* smem, const float* in,
    const ushort* pwW, const float* gamma, const float* beta,
    const float* dww, const float* dwb, const float* pwb,
    float* outp, bool addpos) {
  float*  hbuf = (float*)smem;               // 22*128 fp32
  ushort* wbuf = (ushort*)(smem + 11264);    // 128*152
  ushort* ybuf = (ushort*)(smem + 50176);    // 16*152
  int t = threadIdx.x;
  int r0 = blockIdx.x * 16;
  int s0 = r0 & (SS-1);
  int bb = r0 >> 9;
  stage_w(wbuf, pwW, t);
  int wv = t >> 6, lane = t & 63;
  for (int i = wv; i < 22; i += 4) {               // LN halo rows s0-3 .. s0+18
    int s = s0 - 3 + i;
    if (s < 0 || s >= SS) {
      *(float2*)&hbuf[i*128 + lane*2] = make_float2(0.f, 0.f);
      continue;
    }
    int r = bb*SS + s;
    float2 xv = *(const float2*)&in[(size_t)r*128 + lane*2];
    if (addpos) { xv.x += posenc(s, lane*2); xv.y += posenc(s, lane*2+1); }
    float s1 = xv.x + xv.y, s2 = xv.x*xv.x + xv.y*xv.y;
    #pragma unroll
    for (int o = 32; o > 0; o >>= 1) { s1 += __shfl_xor(s1, o); s2 += __shfl_xor(s2, o); }
    float mu  = s1 * (1.0f/128.0f);
    float var = s2 * (1.0f/128.0f) - mu*mu;
    float inv = rsqrtf(var + LN_EPS);
    float2 gv = *(const float2*)&gamma[lane*2];
    float2 bv = *(const float2*)&beta[lane*2];
    hbuf[i*128 + lane*2]     = (xv.x - mu)*inv*gv.x + bv.x;
    hbuf[i*128 + lane*2 + 1] = (xv.y - mu)*inv*gv.y + bv.y;
  }
  __syncthreads();
  {                                                // depthwise conv, 2 cols/thread
    int cp = t & 63, rg = t >> 6;
    float wa[7], wb2[7];
    #pragma unroll
    for (int k = 0; k < 7; ++k) { wa[k] = dww[(cp*2)*7 + k]; wb2[k] = dww[(cp*2+1)*7 + k]; }
    float ba = dwb[cp*2], bbx = dwb[cp*2+1];
    #pragma unroll
    for (int j = 0; j < 4; ++j) {
      int rr = rg*4 + j;
      float a0 = ba, a1 = bbx;
      #pragma unroll
      for (int k = 0; k < 7; ++k) {
        float2 hv = *(const float2*)&hbuf[(rr + k)*128 + cp*2];
        a0 += hv.x * wa[k];
        a1 += hv.y * wb2[k];
      }
      unsigned pk = (unsigned)f2bf(a0) | ((unsigned)f2bf(a1) << 16);
      *(unsigned*)&ybuf[rr*152 + cp*2] = pk;
    }
  }
  __syncthreads();
  int m = lane & 15, qd = lane >> 4, c0 = wv*32;
  f4 acc0 = {0.f,0.f,0.f,0.f}, acc1 = {0.f,0.f,0.f,0.f};
  mm_tile(ybuf, wbuf, m, qd, c0, acc0, acc1);
  int col0 = c0 + m, col1 = c0 + 16 + m;
  float bv0 = pwb[col0], bv1 = pwb[col1];
  #pragma unroll
  for (int reg = 0; reg < 4; ++reg) {
    int r = r0 + qd*4 + reg;
    int s = s0 + qd*4 + reg;
    float v0 = fmaxf(acc0[reg] + bv0, 0.0f);
    float v1 = fmaxf(acc1[reg] + bv1, 0.0f);
    float rz0 = in[(size_t)r*128 + col0], rz1 = in[(size_t)r*128 + col1];
    if (addpos) { rz0 += posenc(s, col0); rz1 += posenc(s, col1); }
    outp[(size_t)r*128 + col0] = v0 + rz0;
    outp[(size_t)r*128 + col1] = v1 + rz1;
  }
}

// ---------------- LN + QKV projection (3 weight chunks) ----------------
static __device__ void qkv_stage(unsigned char* smem, const float* in,
    const ushort* wqkv, const float* gamma, const float* beta,
    float b0, ushort* qkvout) {
  ushort* abuf = (ushort*)smem;              // 16*152
  ushort* wbuf = (ushort*)(smem + 4864);     // 128*152
  int t = threadIdx.x, wv = t >> 6, lane = t & 63;
  int r0 = blockIdx.x * 16;
  ln_rows_to_abuf(in, r0, gamma, beta, abuf, wv, lane);
  int m = lane & 15, qd = lane >> 4, c0 = wv*32;
  for (int c = 0; c < 3; ++c) {
    __syncthreads();
    stage_w(wbuf, wqkv + c*16384, t);
    __syncthreads();
    f4 acc0 = {0.f,0.f,0.f,0.f}, acc1 = {0.f,0.f,0.f,0.f};
    mm_tile(abuf, wbuf, m, qd, c0, acc0, acc1);
    int col0 = c0 + m, col1 = c0 + 16 + m;
    #pragma unroll
    for (int reg = 0; reg < 4; ++reg) {
      int r = r0 + qd*4 + reg;
      qkvout[(size_t)r*384 + c*128 + col0] = f2bf(acc0[reg] + b0);
      qkvout[(size_t)r*384 + c*128 + col1] = f2bf(acc1[reg] + b0);
    }
  }
}

// ---------------- MFMA attention (V^T in LDS; 128 q-rows/block) ----------------
static __device__ void attn_stage(unsigned char* smem, const ushort* qkv,
    const int* maskp, ushort* att) {
  ushort* kbuf  = (ushort*)smem;             // 512*24
  ushort* vT    = (ushort*)(smem + 24576);   // 16*520
  ushort* pbuf  = (ushort*)(smem + 41216);   // 4*640
  float*  smask = (float*)(smem + 46336);    // 512
  int t = threadIdx.x, blk = blockIdx.x;
  int qc = blk & 3, h = (blk >> 2) & 7, b = blk >> 5;
  for (int i = t; i < 512; i += 256) smask[i] = (float)maskp[b*SS + i];
  for (int i = t; i < 1024; i += 256) {
    int s = i >> 1, half = i & 1;
    *(short8*)&kbuf[s*24 + half*8] =
      *(const short8*)&qkv[(size_t)(b*SS + s)*384 + 128 + h*16 + half*8];
  }
  for (int i = t; i < 2048; i += 256) {      // V transposed: vT[dk][s]
    int s = i >> 2, qu = i & 3;
    short4v v = *(const short4v*)&qkv[(size_t)(b*SS + s)*384 + 256 + h*16 + qu*4];
    #pragma unroll
    for (int j = 0; j < 4; ++j) vT[(qu*4 + j)*520 + s] = (ushort)v[j];
  }
  __syncthreads();
  int wv = t >> 6, lane = t & 63, m = lane & 15, qd = lane >> 4;
  ushort* pb = &pbuf[wv*640];
  f4 zz = {0.f,0.f,0.f,0.f};
  for (int sub = 0; sub < 2; ++sub) {
    int qr0 = qc*128 + sub*64 + wv*16;
    short8 aq = (short8)0;
    if (qd < 2) aq = *(const short8*)&qkv[(size_t)(b*SS + qr0 + m)*384 + h*16 + qd*8];
    f4 oacc = zz;
    float lp0 = 0.f, lp1 = 0.f, lp2 = 0.f, lp3 = 0.f;
    for (int step = 0; step < 16; ++step) {
      int kb = step * 32;
      short8 bk0 = (short8)0, bk1 = (short8)0;
      if (qd < 2) {
        bk0 = *(const short8*)&kbuf[(kb + m)*24 + qd*8];
        bk1 = *(const short8*)&kbuf[(kb + 16 + m)*24 + qd*8];
      }
      f4 s0 = __builtin_amdgcn_mfma_f32_16x16x32_bf16(aq, bk0, zz, 0, 0, 0);
      f4 s1 = __builtin_amdgcn_mfma_f32_16x16x32_bf16(aq, bk1, zz, 0, 0, 0);
      float mk0 = smask[kb + m], mk1 = smask[kb + 16 + m];
      #pragma unroll
      for (int reg = 0; reg < 4; ++reg) {
        float e0 = __expf(s0[reg] * 0.25f) * mk0;
        float e1 = __expf(s1[reg] * 0.25f) * mk1;
        if (reg == 0) lp0 += e0 + e1; else if (reg == 1) lp1 += e0 + e1;
        else if (reg == 2) lp2 += e0 + e1; else lp3 += e0 + e1;
        pb[(qd*4 + reg)*40 + m]      = f2bf(e0);
        pb[(qd*4 + reg)*40 + 16 + m] = f2bf(e1);
      }
      __asm__ volatile("s_waitcnt lgkmcnt(0)" ::: "memory");
      short8 ap = *(const short8*)&pb[m*40 + qd*8];
      short8 bv = *(const short8*)&vT[m*520 + kb + qd*8];
      oacc = __builtin_amdgcn_mfma_f32_16x16x32_bf16(ap, bv, oacc, 0, 0, 0);
    }
    float lp[4] = {lp0, lp1, lp2, lp3};
    #pragma unroll
    for (int reg = 0; reg < 4; ++reg) {
      float l = lp[reg];
      l += __shfl_xor(l, 1); l += __shfl_xor(l, 2);
      l += __shfl_xor(l, 4); l += __shfl_xor(l, 8);
      att[(size_t)(b*SS + qr0 + qd*4 + reg)*128 + h*16 + m] = f2bf(oacc[reg] / l);
    }
  }
}

// ---------------- tail: Wo-proj + res + LN + FFN1 + FFN2 + res ----------------
static __device__ void tail_stage(unsigned char* smem, const ushort* attb,
    const float* resA, const ushort* wo, const ushort* f1w, const ushort* f2w,
    const float* gamma, const float* beta, float b0,
    const float* f1_bias, const float* f2_bias, float* outp) {
  float*  hres = (float*)smem;               // 16*128 fp32
  ushort* wbuf = (ushort*)(smem + 8192);     // 128*152
  ushort* abuf = (ushort*)(smem + 47104);    // 16*152
  ushort* ybuf = (ushort*)(smem + 51968);    // 16*152
  int t = threadIdx.x, wv = t >> 6, lane = t & 63;
  int m = lane & 15, qd = lane >> 4, c0 = wv*32;
  int r0 = blockIdx.x * 16;
  stage_w(wbuf, wo, t);
  for (int i = t; i < 256; i += 256) {
    int row = i >> 4, ch = i & 15;
    *(short8*)&abuf[row*152 + ch*8] = *(const short8*)&attb[(size_t)(r0 + row)*128 + ch*8];
  }
  __syncthreads();
  {  // attention output projection + residual -> hres (fp32, LDS)
    f4 acc0 = {0.f,0.f,0.f,0.f}, acc1 = {0.f,0.f,0.f,0.f};
    mm_tile(abuf, wbuf, m, qd, c0, acc0, acc1);
    int col0 = c0 + m, col1 = c0 + 16 + m;
    #pragma unroll
    for (int reg = 0; reg < 4; ++reg) {
      int lr = qd*4 + reg, r = r0 + lr;
      hres[lr*128 + col0] = acc0[reg] + b0 + resA[(size_t)r*128 + col0];
      hres[lr*128 + col1] = acc1[reg] + b0 + resA[(size_t)r*128 + col1];
    }
  }
  __syncthreads();
  ln_rows_to_abuf(hres, 0, gamma, beta, abuf, wv, lane);
  stage_w(wbuf, f1w, t);
  __syncthreads();
  {  // FFN1 + relu -> ybuf bf16
    f4 acc0 = {0.f,0.f,0.f,0.f}, acc1 = {0.f,0.f,0.f,0.f};
    mm_tile(abuf, wbuf, m, qd, c0, acc0, acc1);
    int col0 = c0 + m, col1 = c0 + 16 + m;
    float bv0 = f1_bias[col0], bv1 = f1_bias[col1];
    #pragma unroll
    for (int reg = 0; reg < 4; ++reg) {
      int lr = qd*4 + reg;
      ybuf[lr*152 + col0] = f2bf(fmaxf(acc0[reg] + bv0, 0.0f));
      ybuf[lr*152 + col1] = f2bf(fmaxf(acc1[reg] + bv1, 0.0f));
    }
  }
  __syncthreads();
  stage_w(wbuf, f2w, t);
  __syncthreads();
  {  // FFN2 + residual(hres) -> out
    f4 acc0 = {0.f,0.f,0.f,0.f}, acc1 = {0.f,0.f,0.f,0.f};
    mm_tile(ybuf, wbuf, m, qd, c0, acc0, acc1);
    int col0 = c0 + m, col1 = c0 + 16 + m;
    float bv0 = f2_bias[col0], bv1 = f2_bias[col1];
    #pragma unroll
    for (int reg = 0; reg < 4; ++reg) {
      int lr = qd*4 + reg, r = r0 + lr;
      outp[(size_t)r*128 + col0] = acc0[reg] + bv0 + hres[lr*128 + col0];
      outp[(size_t)r*128 + col1] = acc1[reg] + bv1 + hres[lr*128 + col1];
    }
  }
}

// ---------------- the mega-kernel ----------------
__global__ __launch_bounds__(256, 2) void mega_kernel(MegaParams p) {
  __shared__ __align__(16) unsigned char smem[57344];
  cg::grid_group grid = cg::this_grid();
  int t = threadIdx.x;

  // S0: weight prep -> bf16 (layout identical to round-2 prep_kernel)
  for (int i = blockIdx.x*256 + t; i < 163840; i += 131072) {
    ushort val;
    if (i < 65536) { val = f2bf(p.pw_w[i]); }
    else {
      int j = i - 65536;
      if (j < 49152) {
        int o = j >> 7, d = j & 127;
        int sec = o >> 7, oo = o & 127, hh = oo >> 4, kk = oo & 15;
        const float* s = (sec == 0) ? p.Wq : ((sec == 1) ? p.Wk : p.Wv);
        val = f2bf(s[hh*2048 + d*16 + kk]);
      } else {
        j -= 49152;
        if (j < 16384) { int o = j >> 7, d = j & 127; val = f2bf(p.Wo[d*128 + o]); }
        else { j -= 16384;
          if (j < 16384) val = f2bf(p.f1_w[j]);
          else val = f2bf(p.f2_w[j - 16384]);
        }
      }
    }
    p.wbf[i] = val;
  }
  grid.sync();

  conv_stage(smem, p.x,    p.wbf,         p.ln_scale,     p.ln_bias,     p.dw_w,       p.dw_b,       p.pw_b,       p.bufB, true);
  grid.sync();
  conv_stage(smem, p.bufB, p.wbf+16384, p.ln_scale+128, p.ln_bias+128, p.dw_w+896,  p.dw_b+128,  p.pw_b+128,  p.bufA, false);
  grid.sync();
  conv_stage(smem, p.bufA, p.wbf+32768, p.ln_scale+256, p.ln_bias+256, p.dw_w+1792, p.dw_b+256,  p.pw_b+256,  p.bufB, false);
  grid.sync();
  conv_stage(smem, p.bufB, p.wbf+49152, p.ln_scale+384, p.ln_bias+384, p.dw_w+2688, p.dw_b+384,  p.pw_b+384,  p.bufA, false);
  grid.sync();

  float b0 = p.att_bias[0];
  qkv_stage(smem, p.bufA, p.wbf+65536, p.ln_scale+512, p.ln_bias+512, b0, p.qkvbuf);
  grid.sync();
  attn_stage(smem, p.qkvbuf, p.mask, p.attbuf);
  grid.sync();
  tail_stage(smem, p.attbuf, p.bufA, p.wbf+114688, p.wbf+131072, p.wbf+147456,
             p.ln_scale+640, p.ln_bias+640, b0, p.f1_b, p.f2_b, p.out);
}

// ---------------- driver ----------------
extern "C" void kernel_launch(void* const* d_in, const int* in_sizes, int n_in,
                              void* d_out, int out_size, void* d_ws, size_t ws_size,
                              hipStream_t stream) {
  MegaParams p;
  p.x        = (const float*)d_in[0];
  p.mask     = (const int*)d_in[1];
  p.ln_scale = (const float*)d_in[2];
  p.ln_bias  = (const float*)d_in[3];
  p.dw_w     = (const float*)d_in[4];
  p.dw_b     = (const float*)d_in[5];
  p.pw_w     = (const float*)d_in[6];
  p.pw_b     = (const float*)d_in[7];
  p.Wq       = (const float*)d_in[8];
  p.Wk       = (const float*)d_in[9];
  p.Wv       = (const float*)d_in[10];
  p.Wo       = (const float*)d_in[11];
  p.att_bias = (const float*)d_in[12];
  p.f1_w     = (const float*)d_in[13];
  p.f1_b     = (const float*)d_in[14];
  p.f2_w     = (const float*)d_in[15];
  p.f2_b     = (const float*)d_in[16];
  p.out      = (float*)d_out;

  p.wbf    = (ushort*)d_ws;                                     // 163840 ushort = 320 KB
  p.bufA   = (float*)((char*)d_ws + 327680);                    // NN*128 f32
  p.bufB   = p.bufA + (size_t)NN*128;                           // NN*128 f32
  p.qkvbuf = (ushort*)(p.bufB + (size_t)NN*128);                // NN*384 bf16
  p.attbuf = p.qkvbuf + (size_t)NN*384;                         // NN*128 bf16

  void* args[] = { &p };
  hipLaunchCooperativeKernel((void*)mega_kernel, dim3(512), dim3(256), args, 0, stream);
}

// Round 4
// 219.594 us; speedup vs baseline: 2.6405x; 2.6405x over previous
//
#include <hip/hip_runtime.h>
#include <math.h>

#define BB 16
#define SS 512
#define NN (BB*SS)   // 8192 rows
#define LN_EPS 1e-5f

typedef __attribute__((ext_vector_type(8))) short short8;
typedef __attribute__((ext_vector_type(4))) float f4;

static __device__ __forceinline__ ushort f2bf(float x) {
  union { float f; unsigned u; } v; v.f = x;
  unsigned r = v.u + 0x7fffu + ((v.u >> 16) & 1u);
  return (ushort)(r >> 16);
}
static __device__ __forceinline__ float bf2f(ushort u) {
  union { unsigned u; float f; } v; v.u = ((unsigned)u) << 16; return v.f;
}
static __device__ __forceinline__ float posenc(int s, int col) {
  const float inc = 0.14619588f;               // log(10000)/63
  int c = col & 63;
  float invf = expf(-inc * (float)c);
  float st = (float)s * invf;
  return (col < 64) ? sinf(st) : cosf(st);
}

// full-width (128-col) MFMA tile: A 16 rows in abuf (stride 152), B in wbuf (stride 152)
static __device__ __forceinline__ void mm_tile2(const ushort* abuf, const ushort* wbuf,
                                                int m, int qd, int c0, f4& acc0, f4& acc1) {
  #pragma unroll
  for (int ks = 0; ks < 4; ++ks) {
    short8 a  = *(const short8*)&abuf[m*152 + ks*32 + qd*8];
    short8 b0 = *(const short8*)&wbuf[(c0 + m)*152 + ks*32 + qd*8];
    short8 b1 = *(const short8*)&wbuf[(c0 + 16 + m)*152 + ks*32 + qd*8];
    acc0 = __builtin_amdgcn_mfma_f32_16x16x32_bf16(a, b0, acc0, 0, 0, 0);
    acc1 = __builtin_amdgcn_mfma_f32_16x16x32_bf16(a, b1, acc1, 0, 0, 0);
  }
}

// ==================================================================
// K1: fused conv x4 (halo recompute) + LN + QKV projection
// block = 16 output rows; needs x rows [s0-12, s0+28)
// ==================================================================
struct ConvParams {
  const float* x; const float* ln_scale; const float* ln_bias;
  const float* dw_w; const float* dw_b; const float* pw_w; const float* pw_b;
  const float* Wq; const float* Wk; const float* Wv; const float* att_bias;
  float* bufA; ushort* qkvbuf;
};

__global__ __launch_bounds__(256, 2) void conv_qkv_kernel(ConvParams p) {
  __shared__ float  cur[40*132];     // 21120 B  (residual chain, fp32)
  __shared__ ushort lnb[40*130];     // 10400 B  (LN output, bf16)
  __shared__ ushort wbuf[64*152];    // 19456 B  (weight half-tile, bf16)
  __shared__ ushort dwbuf[34*152];   // 10336 B  (dwconv out = MFMA A-frags)
  int t = threadIdx.x, wv = t >> 6, lane = t & 63;
  int m = lane & 15, qd = lane >> 4;
  int r0 = blockIdx.x * 16, s0 = r0 & (SS-1), bb = r0 >> 9;

  // ---- fill cur = x + posenc for rows idx 0..39 (s = s0-12+idx) ----
  for (int i = t; i < 40*32; i += 256) {
    int row = i >> 5, q = (i & 31) * 4;
    int s = s0 - 12 + row;
    float4 v = make_float4(0.f, 0.f, 0.f, 0.f);
    if (s >= 0 && s < SS) {
      v = *(const float4*)&p.x[((size_t)(bb*SS + s))*128 + q];
      v.x += posenc(s, q);   v.y += posenc(s, q+1);
      v.z += posenc(s, q+2); v.w += posenc(s, q+3);
    }
    *(float4*)&cur[row*132 + q] = v;
  }
  __syncthreads();

  for (int layer = 0; layer < 4; ++layer) {
    int A = layer*3, Bz = 40 - layer*3;            // LN rows [A, Bz)
    const float* gamma = p.ln_scale + layer*128;
    const float* beta  = p.ln_bias  + layer*128;
    // ---- LN rows -> lnb (bf16); out-of-sequence rows forced to 0 ----
    for (int i = A + wv; i < Bz; i += 4) {
      int s = s0 - 12 + i;
      if (s < 0 || s >= SS) { *(unsigned*)&lnb[i*130 + lane*2] = 0u; continue; }
      float2 xv = *(const float2*)&cur[i*132 + lane*2];
      float s1 = xv.x + xv.y, s2 = xv.x*xv.x + xv.y*xv.y;
      #pragma unroll
      for (int o = 32; o > 0; o >>= 1) { s1 += __shfl_xor(s1, o); s2 += __shfl_xor(s2, o); }
      float mu  = s1 * (1.0f/128.0f);
      float var = s2 * (1.0f/128.0f) - mu*mu;
      float inv = rsqrtf(var + LN_EPS);
      float2 gv = *(const float2*)&gamma[lane*2];
      float2 bv = *(const float2*)&beta[lane*2];
      float n0 = (xv.x - mu)*inv*gv.x + bv.x;
      float n1 = (xv.y - mu)*inv*gv.y + bv.y;
      *(unsigned*)&lnb[i*130 + lane*2] = (unsigned)f2bf(n0) | ((unsigned)f2bf(n1) << 16);
    }
    __syncthreads();
    // ---- depthwise conv rows [A+3, Bz-3) -> dwbuf (bf16, A-frag layout) ----
    int rows = Bz - A - 6;
    {
      int c = t & 127;
      const float* dwW = p.dw_w + layer*896;
      float w0 = dwW[c*7+0], w1 = dwW[c*7+1], w2 = dwW[c*7+2], w3 = dwW[c*7+3];
      float w4 = dwW[c*7+4], w5 = dwW[c*7+5], w6 = dwW[c*7+6];
      float bsv = p.dw_b[layer*128 + c];
      for (int j = t >> 7; j < rows; j += 2) {
        int idx = A + 3 + j;
        float acc = bsv;
        acc += bf2f(lnb[(idx-3)*130 + c]) * w0;
        acc += bf2f(lnb[(idx-2)*130 + c]) * w1;
        acc += bf2f(lnb[(idx-1)*130 + c]) * w2;
        acc += bf2f(lnb[(idx  )*130 + c]) * w3;
        acc += bf2f(lnb[(idx+1)*130 + c]) * w4;
        acc += bf2f(lnb[(idx+2)*130 + c]) * w5;
        acc += bf2f(lnb[(idx+3)*130 + c]) * w6;
        dwbuf[j*152 + c] = f2bf(acc);
      }
    }
    __syncthreads();
    // ---- pointwise conv (MFMA) in two 64-col halves; relu + residual into cur ----
    int ntile = (rows + 15) >> 4;
    const float* pwW = p.pw_w + layer*16384;
    const float* pwb = p.pw_b + layer*128;
    for (int half = 0; half < 2; ++half) {
      for (int i = t; i < 2048; i += 256) {         // stage 64x128 weights fp32->bf16
        int o = i >> 5, dq = (i & 31) * 4;
        float4 w4v = *(const float4*)&pwW[(half*64 + o)*128 + dq];
        unsigned lo = (unsigned)f2bf(w4v.x) | ((unsigned)f2bf(w4v.y) << 16);
        unsigned hi = (unsigned)f2bf(w4v.z) | ((unsigned)f2bf(w4v.w) << 16);
        *(uint2*)&wbuf[o*152 + dq] = make_uint2(lo, hi);
      }
      __syncthreads();
      for (int tile = 0; tile < ntile; ++tile) {
        int row0 = tile * 16;
        f4 acc = {0.f,0.f,0.f,0.f};
        short8 a = (short8)0;
        if (row0 + m < rows) { /* guarded below per k-step */ }
        #pragma unroll
        for (int ks = 0; ks < 4; ++ks) {
          short8 av = (short8)0;
          if (row0 + m < rows) av = *(const short8*)&dwbuf[(row0 + m)*152 + ks*32 + qd*8];
          short8 bv = *(const short8*)&wbuf[(wv*16 + m)*152 + ks*32 + qd*8];
          acc = __builtin_amdgcn_mfma_f32_16x16x32_bf16(av, bv, acc, 0, 0, 0);
        }
        (void)a;
        int col = half*64 + wv*16 + m;
        float bv0 = pwb[col];
        #pragma unroll
        for (int reg = 0; reg < 4; ++reg) {
          int lr = row0 + qd*4 + reg;
          if (lr < rows) {
            int idx = A + 3 + lr;
            cur[idx*132 + col] = fmaxf(acc[reg] + bv0, 0.0f) + cur[idx*132 + col];
          }
        }
      }
      __syncthreads();
    }
  }

  // ---- conv output rows are cur[12..28); write residual to bufA ----
  for (int i = t; i < 16*32; i += 256) {
    int row = i >> 5, q = (i & 31) * 4;
    *(float4*)&p.bufA[((size_t)(r0 + row))*128 + q] = *(const float4*)&cur[(12 + row)*132 + q];
  }
  // ---- attention LN rows 12..27 -> abuf (reuse dwbuf) ----
  {
    const float* gamma = p.ln_scale + 4*128;
    const float* beta  = p.ln_bias  + 4*128;
    for (int i = wv; i < 16; i += 4) {
      int idx = 12 + i;
      float2 xv = *(const float2*)&cur[idx*132 + lane*2];
      float s1 = xv.x + xv.y, s2 = xv.x*xv.x + xv.y*xv.y;
      #pragma unroll
      for (int o = 32; o > 0; o >>= 1) { s1 += __shfl_xor(s1, o); s2 += __shfl_xor(s2, o); }
      float mu  = s1 * (1.0f/128.0f);
      float var = s2 * (1.0f/128.0f) - mu*mu;
      float inv = rsqrtf(var + LN_EPS);
      float2 gv = *(const float2*)&gamma[lane*2];
      float2 bv = *(const float2*)&beta[lane*2];
      float n0 = (xv.x - mu)*inv*gv.x + bv.x;
      float n1 = (xv.y - mu)*inv*gv.y + bv.y;
      *(unsigned*)&dwbuf[i*152 + lane*2] = (unsigned)f2bf(n0) | ((unsigned)f2bf(n1) << 16);
    }
  }
  __syncthreads();
  // ---- QKV projection: 3 matrices x 2 halves ----
  float b0 = p.att_bias[0];
  for (int c = 0; c < 3; ++c) {
    const float* Wsrc = (c == 0) ? p.Wq : ((c == 1) ? p.Wk : p.Wv);
    for (int half = 0; half < 2; ++half) {
      for (int i = t; i < 8192; i += 256) {          // W[o][d] = Wsrc[h,d,k], o=h*16+k
        int o = half*64 + (i >> 7), d = i & 127;
        wbuf[(o - half*64)*152 + d] = f2bf(Wsrc[(o >> 4)*2048 + d*16 + (o & 15)]);
      }
      __syncthreads();
      f4 acc = {0.f,0.f,0.f,0.f};
      #pragma unroll
      for (int ks = 0; ks < 4; ++ks) {
        short8 av = *(const short8*)&dwbuf[m*152 + ks*32 + qd*8];
        short8 bv = *(const short8*)&wbuf[(wv*16 + m)*152 + ks*32 + qd*8];
        acc = __builtin_amdgcn_mfma_f32_16x16x32_bf16(av, bv, acc, 0, 0, 0);
      }
      int col = half*64 + wv*16 + m;
      #pragma unroll
      for (int reg = 0; reg < 4; ++reg)
        p.qkvbuf[((size_t)(r0 + qd*4 + reg))*384 + c*128 + col] = f2bf(acc[reg] + b0);
      __syncthreads();
    }
  }
}

// ==================================================================
// K2: MFMA attention (V^T in LDS; 128 q-rows/block)
// ==================================================================
__global__ __launch_bounds__(256, 2) void attn_kernel(
    const ushort* __restrict__ qkv, const int* __restrict__ maskp,
    ushort* __restrict__ att) {
  __shared__ ushort kbuf[512*24];
  __shared__ ushort vT[16*520];
  __shared__ ushort pbuf[4*640];
  __shared__ float  smask[512];
  typedef __attribute__((ext_vector_type(4))) short short4v;
  int t = threadIdx.x, blk = blockIdx.x;
  int qc = blk & 3, h = (blk >> 2) & 7, b = blk >> 5;
  for (int i = t; i < 512; i += 256) smask[i] = (float)maskp[b*SS + i];
  for (int i = t; i < 1024; i += 256) {
    int s = i >> 1, half = i & 1;
    *(short8*)&kbuf[s*24 + half*8] =
      *(const short8*)&qkv[(size_t)(b*SS + s)*384 + 128 + h*16 + half*8];
  }
  for (int i = t; i < 2048; i += 256) {
    int s = i >> 2, qu = i & 3;
    short4v v = *(const short4v*)&qkv[(size_t)(b*SS + s)*384 + 256 + h*16 + qu*4];
    #pragma unroll
    for (int j = 0; j < 4; ++j) vT[(qu*4 + j)*520 + s] = (ushort)v[j];
  }
  __syncthreads();
  int wv = t >> 6, lane = t & 63, m = lane & 15, qd = lane >> 4;
  ushort* pb = &pbuf[wv*640];
  f4 zz = {0.f,0.f,0.f,0.f};
  for (int sub = 0; sub < 2; ++sub) {
    int qr0 = qc*128 + sub*64 + wv*16;
    short8 aq = (short8)0;
    if (qd < 2) aq = *(const short8*)&qkv[(size_t)(b*SS + qr0 + m)*384 + h*16 + qd*8];
    f4 oacc = zz;
    float lp0 = 0.f, lp1 = 0.f, lp2 = 0.f, lp3 = 0.f;
    for (int step = 0; step < 16; ++step) {
      int kb = step * 32;
      short8 bk0 = (short8)0, bk1 = (short8)0;
      if (qd < 2) {
        bk0 = *(const short8*)&kbuf[(kb + m)*24 + qd*8];
        bk1 = *(const short8*)&kbuf[(kb + 16 + m)*24 + qd*8];
      }
      f4 s0 = __builtin_amdgcn_mfma_f32_16x16x32_bf16(aq, bk0, zz, 0, 0, 0);
      f4 s1 = __builtin_amdgcn_mfma_f32_16x16x32_bf16(aq, bk1, zz, 0, 0, 0);
      float mk0 = smask[kb + m], mk1 = smask[kb + 16 + m];
      #pragma unroll
      for (int reg = 0; reg < 4; ++reg) {
        float e0 = __expf(s0[reg] * 0.25f) * mk0;
        float e1 = __expf(s1[reg] * 0.25f) * mk1;
        if (reg == 0) lp0 += e0 + e1; else if (reg == 1) lp1 += e0 + e1;
        else if (reg == 2) lp2 += e0 + e1; else lp3 += e0 + e1;
        pb[(qd*4 + reg)*40 + m]      = f2bf(e0);
        pb[(qd*4 + reg)*40 + 16 + m] = f2bf(e1);
      }
      __asm__ volatile("s_waitcnt lgkmcnt(0)" ::: "memory");
      short8 ap = *(const short8*)&pb[m*40 + qd*8];
      short8 bv = *(const short8*)&vT[m*520 + kb + qd*8];
      oacc = __builtin_amdgcn_mfma_f32_16x16x32_bf16(ap, bv, oacc, 0, 0, 0);
    }
    float lp[4] = {lp0, lp1, lp2, lp3};
    #pragma unroll
    for (int reg = 0; reg < 4; ++reg) {
      float l = lp[reg];
      l += __shfl_xor(l, 1); l += __shfl_xor(l, 2);
      l += __shfl_xor(l, 4); l += __shfl_xor(l, 8);
      att[(size_t)(b*SS + qr0 + qd*4 + reg)*128 + h*16 + m] = f2bf(oacc[reg] / l);
    }
  }
}

// ==================================================================
// K3: Wo-proj + residual + LN + FFN1 + FFN2 + residual
// ==================================================================
struct TailParams {
  const ushort* attb; const float* resA;
  const float* Wo; const float* f1w; const float* f2w;
  const float* ln_scale; const float* ln_bias; const float* att_bias;
  const float* f1b; const float* f2b; float* out;
};

__global__ __launch_bounds__(256, 2) void tail_kernel(TailParams p) {
  __shared__ float  hres[16*128];    // 8192 B
  __shared__ ushort wbuf[128*152];   // 38912 B
  __shared__ ushort abuf[16*152];    // 4864 B
  __shared__ ushort ybuf[16*152];    // 4864 B
  int t = threadIdx.x, wv = t >> 6, lane = t & 63;
  int m = lane & 15, qd = lane >> 4, c0 = wv*32;
  int r0 = blockIdx.x * 16;
  float b0 = p.att_bias[0];

  // stage Wo^T (coalesced global read, transposed LDS write)
  for (int i = t; i < 16384; i += 256) {
    int o = i & 127, d = i >> 7;
    wbuf[o*152 + d] = f2bf(p.Wo[d*128 + o]);
  }
  for (int i = t; i < 256; i += 256) {
    int row = i >> 4, ch = i & 15;
    *(short8*)&abuf[row*152 + ch*8] = *(const short8*)&p.attb[(size_t)(r0 + row)*128 + ch*8];
  }
  __syncthreads();
  {  // attention output projection + residual -> hres
    f4 acc0 = {0.f,0.f,0.f,0.f}, acc1 = {0.f,0.f,0.f,0.f};
    mm_tile2(abuf, wbuf, m, qd, c0, acc0, acc1);
    int col0 = c0 + m, col1 = c0 + 16 + m;
    #pragma unroll
    for (int reg = 0; reg < 4; ++reg) {
      int lr = qd*4 + reg, r = r0 + lr;
      hres[lr*128 + col0] = acc0[reg] + b0 + p.resA[(size_t)r*128 + col0];
      hres[lr*128 + col1] = acc1[reg] + b0 + p.resA[(size_t)r*128 + col1];
    }
  }
  __syncthreads();
  {  // LN(hres) -> abuf
    const float* gamma = p.ln_scale + 5*128;
    const float* beta  = p.ln_bias  + 5*128;
    for (int i = wv; i < 16; i += 4) {
      float2 xv = *(const float2*)&hres[i*128 + lane*2];
      float s1 = xv.x + xv.y, s2 = xv.x*xv.x + xv.y*xv.y;
      #pragma unroll
      for (int o = 32; o > 0; o >>= 1) { s1 += __shfl_xor(s1, o); s2 += __shfl_xor(s2, o); }
      float mu  = s1 * (1.0f/128.0f);
      float var = s2 * (1.0f/128.0f) - mu*mu;
      float inv = rsqrtf(var + LN_EPS);
      float2 gv = *(const float2*)&gamma[lane*2];
      float2 bv = *(const float2*)&beta[lane*2];
      float n0 = (xv.x - mu)*inv*gv.x + bv.x;
      float n1 = (xv.y - mu)*inv*gv.y + bv.y;
      *(unsigned*)&abuf[i*152 + lane*2] = (unsigned)f2bf(n0) | ((unsigned)f2bf(n1) << 16);
    }
  }
  for (int i = t; i < 4096; i += 256) {   // stage f1 (contiguous)
    int o = i >> 5, dq = (i & 31) * 4;
    float4 w4v = *(const float4*)&p.f1w[o*128 + dq];
    unsigned lo = (unsigned)f2bf(w4v.x) | ((unsigned)f2bf(w4v.y) << 16);
    unsigned hi = (unsigned)f2bf(w4v.z) | ((unsigned)f2bf(w4v.w) << 16);
    *(uint2*)&wbuf[o*152 + dq] = make_uint2(lo, hi);
  }
  __syncthreads();
  {  // FFN1 + relu -> ybuf
    f4 acc0 = {0.f,0.f,0.f,0.f}, acc1 = {0.f,0.f,0.f,0.f};
    mm_tile2(abuf, wbuf, m, qd, c0, acc0, acc1);
    int col0 = c0 + m, col1 = c0 + 16 + m;
    float bv0 = p.f1b[col0], bv1 = p.f1b[col1];
    #pragma unroll
    for (int reg = 0; reg < 4; ++reg) {
      int lr = qd*4 + reg;
      ybuf[lr*152 + col0] = f2bf(fmaxf(acc0[reg] + bv0, 0.0f));
      ybuf[lr*152 + col1] = f2bf(fmaxf(acc1[reg] + bv1, 0.0f));
    }
  }
  __syncthreads();
  for (int i = t; i < 4096; i += 256) {   // stage f2
    int o = i >> 5, dq = (i & 31) * 4;
    float4 w4v = *(const float4*)&p.f2w[o*128 + dq];
    unsigned lo = (unsigned)f2bf(w4v.x) | ((unsigned)f2bf(w4v.y) << 16);
    unsigned hi = (unsigned)f2bf(w4v.z) | ((unsigned)f2bf(w4v.w) << 16);
    *(uint2*)&wbuf[o*152 + dq] = make_uint2(lo, hi);
  }
  __syncthreads();
  {  // FFN2 + residual -> out
    f4 acc0 = {0.f,0.f,0.f,0.f}, acc1 = {0.f,0.f,0.f,0.f};
    mm_tile2(ybuf, wbuf, m, qd, c0, acc0, acc1);
    int col0 = c0 + m, col1 = c0 + 16 + m;
    float bv0 = p.f2b[col0], bv1 = p.f2b[col1];
    #pragma unroll
    for (int reg = 0; reg < 4; ++reg) {
      int lr = qd*4 + reg, r = r0 + lr;
      p.out[(size_t)r*128 + col0] = acc0[reg] + bv0 + hres[lr*128 + col0];
      p.out[(size_t)r*128 + col1] = acc1[reg] + bv1 + hres[lr*128 + col1];
    }
  }
}

// ==================================================================
extern "C" void kernel_launch(void* const* d_in, const int* in_sizes, int n_in,
                              void* d_out, int out_size, void* d_ws, size_t ws_size,
                              hipStream_t stream) {
  ConvParams cp;
  cp.x        = (const float*)d_in[0];
  cp.ln_scale = (const float*)d_in[2];
  cp.ln_bias  = (const float*)d_in[3];
  cp.dw_w     = (const float*)d_in[4];
  cp.dw_b     = (const float*)d_in[5];
  cp.pw_w     = (const float*)d_in[6];
  cp.pw_b     = (const float*)d_in[7];
  cp.Wq       = (const float*)d_in[8];
  cp.Wk       = (const float*)d_in[9];
  cp.Wv       = (const float*)d_in[10];
  cp.att_bias = (const float*)d_in[12];

  float*  bufA   = (float*)d_ws;                          // NN*128 f32
  ushort* qkvbuf = (ushort*)(bufA + (size_t)NN*128);      // NN*384 bf16
  ushort* attbuf = qkvbuf + (size_t)NN*384;               // NN*128 bf16
  cp.bufA = bufA; cp.qkvbuf = qkvbuf;

  hipLaunchKernelGGL(conv_qkv_kernel, dim3(NN/16), dim3(256), 0, stream, cp);

  hipLaunchKernelGGL(attn_kernel, dim3(BB*8*4), dim3(256), 0, stream,
                     qkvbuf, (const int*)d_in[1], attbuf);

  TailParams tp;
  tp.attb = attbuf; tp.resA = bufA;
  tp.Wo  = (const float*)d_in[11];
  tp.f1w = (const float*)d_in[13];
  tp.f2w = (const float*)d_in[15];
  tp.ln_scale = (const float*)d_in[2];
  tp.ln_bias  = (const float*)d_in[3];
  tp.att_bias = (const float*)d_in[12];
  tp.f1b = (const float*)d_in[14];
  tp.f2b = (const float*)d_in[16];
  tp.out = (float*)d_out;
  hipLaunchKernelGGL(tail_kernel, dim3(NN/16), dim3(256), 0, stream, tp);
}

// Round 6
// 160.166 us; speedup vs baseline: 3.6202x; 1.3710x over previous
//
#include <hip/hip_runtime.h>
#include <math.h>

#define BB 16
#define SS 512
#define NN (BB*SS)   // 8192 rows
#define LN_EPS 1e-5f

typedef __attribute__((ext_vector_type(8))) short short8;
typedef __attribute__((ext_vector_type(4))) short short4v;
typedef __attribute__((ext_vector_type(4))) float f4;

static __device__ __forceinline__ ushort f2bf(float x) {
  union { float f; unsigned u; } v; v.f = x;
  unsigned r = v.u + 0x7fffu + ((v.u >> 16) & 1u);
  return (ushort)(r >> 16);
}
static __device__ __forceinline__ float bf2fu(ushort u) {
  union { unsigned u; float f; } v; v.u = ((unsigned)u) << 16; return v.f;
}
static __device__ __forceinline__ float posenc(int s, int col) {
  const float inc = 0.14619588f;               // log(10000)/63
  int c = col & 63;
  float invf = expf(-inc * (float)c);
  float st = (float)s * invf;
  return (col < 64) ? sinf(st) : cosf(st);
}

// ================= prep: weights -> bf16 (q,k as hi/lo pairs) =================
// dst (ushort): [0:65536) pw 4x[o][d]
// [65536:81920) wq_hi   [81920:98304) wq_lo    (o = h*16+k, pre layout [o][d])
// [98304:114688) wk_hi  [114688:131072) wk_lo
// [131072:147456) wv    [147456:163840) Wo^T [o][d]
// [163840:180224) f1    [180224:196608) f2
__global__ __launch_bounds__(256) void prep_kernel(
    const float* __restrict__ pw, const float* __restrict__ Wq,
    const float* __restrict__ Wk, const float* __restrict__ Wv,
    const float* __restrict__ Wo, const float* __restrict__ f1,
    const float* __restrict__ f2, ushort* __restrict__ dst) {
  int i = blockIdx.x * 256 + threadIdx.x;
  if (i < 65536) { dst[i] = f2bf(pw[i]); return; }
  int j = i - 65536;
  if (j < 65536) {                        // Wq / Wk hi+lo
    const float* W = (j < 32768) ? Wq : Wk;
    int jj = j & 32767;
    int part = jj >> 14;                  // 0=hi 1=lo
    int e = jj & 16383;
    int o = e >> 7, d = e & 127;
    float w = W[(o >> 4)*2048 + d*16 + (o & 15)];
    ushort hi = f2bf(w);
    dst[i] = part ? f2bf(w - bf2fu(hi)) : hi;
    return;
  }
  j -= 65536;
  if (j < 16384) {                        // Wv
    int o = j >> 7, d = j & 127;
    dst[i] = f2bf(Wv[(o >> 4)*2048 + d*16 + (o & 15)]); return;
  }
  j -= 16384;
  if (j < 16384) { int o = j >> 7, d = j & 127; dst[i] = f2bf(Wo[d*128 + o]); return; }
  j -= 16384;
  if (j < 16384) { dst[i] = f2bf(f1[j]); return; }
  j -= 16384;
  dst[i] = f2bf(f2[j]);
}

// ==================================================================
// K1: conv x4 (halo recompute, fp32 LN->dwconv) + attn-LN + QKV (q,k split)
// ==================================================================
struct ConvParams {
  const float* x; const float* ln_scale; const float* ln_bias;
  const float* dw_w; const float* dw_b; const float* pw_b;
  const float* att_bias;
  const ushort* pw_bf;
  const ushort* wq_hi; const ushort* wq_lo;
  const ushort* wk_hi; const ushort* wk_lo; const ushort* wv_bf;
  float* bufA; ushort* qkvbuf;
};

__global__ __launch_bounds__(256, 2) void conv_qkv_kernel(ConvParams p) {
  __shared__ float  cur[40*132];     // 21120 B (residual chain fp32)
  __shared__ float  lnb[40*132];     // 21120 B (LN out fp32)
  __shared__ ushort dwbuf[34*152];   // 10336 B (dwconv out / A-frags)
  int t = threadIdx.x, wv = t >> 6, lane = t & 63;
  int m = lane & 15, qd = lane >> 4;
  int c0 = wv * 32;
  int r0 = blockIdx.x * 16, s0 = r0 & (SS-1), bb = r0 >> 9;
  f4 zz = {0.f,0.f,0.f,0.f};

  // ---- fill cur = x + posenc, rows 0..39 (s = s0-12+row) ----
  for (int i = t; i < 40*32; i += 256) {
    int row = i >> 5, q = (i & 31) * 4;
    int s = s0 - 12 + row;
    float4 v = make_float4(0.f, 0.f, 0.f, 0.f);
    if (s >= 0 && s < SS) {
      v = *(const float4*)&p.x[((size_t)(bb*SS + s))*128 + q];
      v.x += posenc(s, q);   v.y += posenc(s, q+1);
      v.z += posenc(s, q+2); v.w += posenc(s, q+3);
    }
    *(float4*)&cur[row*132 + q] = v;
  }
  __syncthreads();

  for (int layer = 0; layer < 4; ++layer) {
    int A = layer*3, Bz = 40 - layer*3;
    const float* gamma = p.ln_scale + layer*128;
    const float* beta  = p.ln_bias  + layer*128;
    // ---- LN window [A,Bz): 16 rows/pass, 16-lane segments, fp32 output ----
    int npass = (Bz - A + 15) >> 4;
    for (int ps = 0; ps < npass; ++ps) {
      int i = A + ps*16 + wv*4 + qd;
      if (i < Bz) {
        int s = s0 - 12 + i;
        if (s < 0 || s >= SS) {
          *(float4*)&lnb[i*132 + m*8]     = make_float4(0.f,0.f,0.f,0.f);
          *(float4*)&lnb[i*132 + m*8 + 4] = make_float4(0.f,0.f,0.f,0.f);
        } else {
          float4 xa = *(const float4*)&cur[i*132 + m*8];
          float4 xb = *(const float4*)&cur[i*132 + m*8 + 4];
          float s1 = xa.x+xa.y+xa.z+xa.w + xb.x+xb.y+xb.z+xb.w;
          float s2 = xa.x*xa.x+xa.y*xa.y+xa.z*xa.z+xa.w*xa.w
                   + xb.x*xb.x+xb.y*xb.y+xb.z*xb.z+xb.w*xb.w;
          #pragma unroll
          for (int o = 1; o < 16; o <<= 1) { s1 += __shfl_xor(s1, o); s2 += __shfl_xor(s2, o); }
          float mu  = s1 * (1.0f/128.0f);
          float var = s2 * (1.0f/128.0f) - mu*mu;
          float inv = rsqrtf(var + LN_EPS);
          float4 ga = *(const float4*)&gamma[m*8], gb = *(const float4*)&gamma[m*8+4];
          float4 ba = *(const float4*)&beta[m*8],  bb2 = *(const float4*)&beta[m*8+4];
          float4 na, nb;
          na.x = (xa.x-mu)*inv*ga.x + ba.x;  na.y = (xa.y-mu)*inv*ga.y + ba.y;
          na.z = (xa.z-mu)*inv*ga.z + ba.z;  na.w = (xa.w-mu)*inv*ga.w + ba.w;
          nb.x = (xb.x-mu)*inv*gb.x + bb2.x; nb.y = (xb.y-mu)*inv*gb.y + bb2.y;
          nb.z = (xb.z-mu)*inv*gb.z + bb2.z; nb.w = (xb.w-mu)*inv*gb.w + bb2.w;
          *(float4*)&lnb[i*132 + m*8]     = na;
          *(float4*)&lnb[i*132 + m*8 + 4] = nb;
        }
      }
    }
    // hoist pointwise B-fragments global->VGPR
    const ushort* pwL = p.pw_bf + layer*16384;
    short8 wb0[4], wb1[4];
    #pragma unroll
    for (int ks = 0; ks < 4; ++ks) {
      wb0[ks] = *(const short8*)&pwL[(c0 + m)*128 + ks*32 + qd*8];
      wb1[ks] = *(const short8*)&pwL[(c0 + 16 + m)*128 + ks*32 + qd*8];
    }
    __syncthreads();
    // ---- depthwise conv rows [A+3, Bz-3): fp32 in, bf16 out ----
    int rows = Bz - A - 6;
    {
      int cp = t & 63;
      const float* dwW = p.dw_w + layer*896;
      float wa[7], wb[7];
      #pragma unroll
      for (int k = 0; k < 7; ++k) { wa[k] = dwW[(cp*2)*7 + k]; wb[k] = dwW[(cp*2+1)*7 + k]; }
      float ba = p.dw_b[layer*128 + cp*2], bbv = p.dw_b[layer*128 + cp*2 + 1];
      for (int j = t >> 6; j < rows; j += 4) {
        int idx = A + 3 + j;
        float a0 = ba, a1 = bbv;
        #pragma unroll
        for (int k = 0; k < 7; ++k) {
          float2 hv = *(const float2*)&lnb[(idx - 3 + k)*132 + cp*2];
          a0 += hv.x * wa[k];
          a1 += hv.y * wb[k];
        }
        *(unsigned*)&dwbuf[j*152 + cp*2] = (unsigned)f2bf(a0) | ((unsigned)f2bf(a1) << 16);
      }
    }
    __syncthreads();
    // ---- pointwise MFMA + relu + residual into cur ----
    int ntile = (rows + 15) >> 4;
    const float* pwb = p.pw_b + layer*128;
    float bv0 = pwb[c0 + m], bv1 = pwb[c0 + 16 + m];
    for (int tile = 0; tile < ntile; ++tile) {
      int row0 = tile * 16;
      f4 acc0 = zz, acc1 = zz;
      #pragma unroll
      for (int ks = 0; ks < 4; ++ks) {
        short8 av = (short8)0;
        if (row0 + m < rows) av = *(const short8*)&dwbuf[(row0 + m)*152 + ks*32 + qd*8];
        acc0 = __builtin_amdgcn_mfma_f32_16x16x32_bf16(av, wb0[ks], acc0, 0, 0, 0);
        acc1 = __builtin_amdgcn_mfma_f32_16x16x32_bf16(av, wb1[ks], acc1, 0, 0, 0);
      }
      #pragma unroll
      for (int reg = 0; reg < 4; ++reg) {
        int lr = row0 + qd*4 + reg;
        if (lr < rows) {
          int idx = A + 3 + lr;
          cur[idx*132 + c0 + m]      = fmaxf(acc0[reg] + bv0, 0.0f) + cur[idx*132 + c0 + m];
          cur[idx*132 + c0 + 16 + m] = fmaxf(acc1[reg] + bv1, 0.0f) + cur[idx*132 + c0 + 16 + m];
        }
      }
    }
    __syncthreads();
  }

  // ---- conv output rows cur[12..28) -> bufA ----
  for (int i = t; i < 16*32; i += 256) {
    int row = i >> 5, q = (i & 31) * 4;
    *(float4*)&p.bufA[((size_t)(r0 + row))*128 + q] = *(const float4*)&cur[(12 + row)*132 + q];
  }
  // ---- attn LN rows 12..27 -> dwbuf hi rows [0,16), lo rows [16,32) ----
  {
    const float* gamma = p.ln_scale + 4*128;
    const float* beta  = p.ln_bias  + 4*128;
    int i = wv*4 + qd;
    int idx = 12 + i;
    float4 xa = *(const float4*)&cur[idx*132 + m*8];
    float4 xb = *(const float4*)&cur[idx*132 + m*8 + 4];
    float s1 = xa.x+xa.y+xa.z+xa.w + xb.x+xb.y+xb.z+xb.w;
    float s2 = xa.x*xa.x+xa.y*xa.y+xa.z*xa.z+xa.w*xa.w
             + xb.x*xb.x+xb.y*xb.y+xb.z*xb.z+xb.w*xb.w;
    #pragma unroll
    for (int o = 1; o < 16; o <<= 1) { s1 += __shfl_xor(s1, o); s2 += __shfl_xor(s2, o); }
    float mu  = s1 * (1.0f/128.0f);
    float var = s2 * (1.0f/128.0f) - mu*mu;
    float inv = rsqrtf(var + LN_EPS);
    float4 ga = *(const float4*)&gamma[m*8], gb = *(const float4*)&gamma[m*8+4];
    float4 ba = *(const float4*)&beta[m*8],  bb2 = *(const float4*)&beta[m*8+4];
    float n[8];
    n[0]=(xa.x-mu)*inv*ga.x+ba.x;  n[1]=(xa.y-mu)*inv*ga.y+ba.y;
    n[2]=(xa.z-mu)*inv*ga.z+ba.z;  n[3]=(xa.w-mu)*inv*ga.w+ba.w;
    n[4]=(xb.x-mu)*inv*gb.x+bb2.x; n[5]=(xb.y-mu)*inv*gb.y+bb2.y;
    n[6]=(xb.z-mu)*inv*gb.z+bb2.z; n[7]=(xb.w-mu)*inv*gb.w+bb2.w;
    #pragma unroll
    for (int e = 0; e < 4; ++e) {
      ushort h0 = f2bf(n[e*2]), h1 = f2bf(n[e*2+1]);
      ushort l0 = f2bf(n[e*2] - bf2fu(h0)), l1 = f2bf(n[e*2+1] - bf2fu(h1));
      *(unsigned*)&dwbuf[i*152 + m*8 + e*2]        = (unsigned)h0 | ((unsigned)h1 << 16);
      *(unsigned*)&dwbuf[(16 + i)*152 + m*8 + e*2] = (unsigned)l0 | ((unsigned)l1 << 16);
    }
  }
  __syncthreads();
  float b0 = p.att_bias[0];
  short8 afh[4], afl[4];
  #pragma unroll
  for (int ks = 0; ks < 4; ++ks) {
    afh[ks] = *(const short8*)&dwbuf[m*152 + ks*32 + qd*8];
    afl[ks] = *(const short8*)&dwbuf[(16 + m)*152 + ks*32 + qd*8];
  }
  // ---- q (split, pre-scaled 0.25) ----
  {
    f4 a0 = zz, a1 = zz;
    #pragma unroll
    for (int ks = 0; ks < 4; ++ks) {
      short8 bh0 = *(const short8*)&p.wq_hi[(c0 + m)*128 + ks*32 + qd*8];
      short8 bh1 = *(const short8*)&p.wq_hi[(c0 + 16 + m)*128 + ks*32 + qd*8];
      short8 bl0 = *(const short8*)&p.wq_lo[(c0 + m)*128 + ks*32 + qd*8];
      short8 bl1 = *(const short8*)&p.wq_lo[(c0 + 16 + m)*128 + ks*32 + qd*8];
      a0 = __builtin_amdgcn_mfma_f32_16x16x32_bf16(afh[ks], bh0, a0, 0, 0, 0);
      a0 = __builtin_amdgcn_mfma_f32_16x16x32_bf16(afh[ks], bl0, a0, 0, 0, 0);
      a0 = __builtin_amdgcn_mfma_f32_16x16x32_bf16(afl[ks], bh0, a0, 0, 0, 0);
      a1 = __builtin_amdgcn_mfma_f32_16x16x32_bf16(afh[ks], bh1, a1, 0, 0, 0);
      a1 = __builtin_amdgcn_mfma_f32_16x16x32_bf16(afh[ks], bl1, a1, 0, 0, 0);
      a1 = __builtin_amdgcn_mfma_f32_16x16x32_bf16(afl[ks], bh1, a1, 0, 0, 0);
    }
    #pragma unroll
    for (int reg = 0; reg < 4; ++reg) {
      size_t r = (size_t)(r0 + qd*4 + reg);
      float v0 = (a0[reg] + b0) * 0.25f, v1 = (a1[reg] + b0) * 0.25f;
      ushort h0 = f2bf(v0), h1 = f2bf(v1);
      p.qkvbuf[r*640 + c0 + m]            = h0;
      p.qkvbuf[r*640 + c0 + 16 + m]       = h1;
      p.qkvbuf[r*640 + 128 + c0 + m]      = f2bf(v0 - bf2fu(h0));
      p.qkvbuf[r*640 + 128 + c0 + 16 + m] = f2bf(v1 - bf2fu(h1));
    }
  }
  // ---- k (split) ----
  {
    f4 a0 = zz, a1 = zz;
    #pragma unroll
    for (int ks = 0; ks < 4; ++ks) {
      short8 bh0 = *(const short8*)&p.wk_hi[(c0 + m)*128 + ks*32 + qd*8];
      short8 bh1 = *(const short8*)&p.wk_hi[(c0 + 16 + m)*128 + ks*32 + qd*8];
      short8 bl0 = *(const short8*)&p.wk_lo[(c0 + m)*128 + ks*32 + qd*8];
      short8 bl1 = *(const short8*)&p.wk_lo[(c0 + 16 + m)*128 + ks*32 + qd*8];
      a0 = __builtin_amdgcn_mfma_f32_16x16x32_bf16(afh[ks], bh0, a0, 0, 0, 0);
      a0 = __builtin_amdgcn_mfma_f32_16x16x32_bf16(afh[ks], bl0, a0, 0, 0, 0);
      a0 = __builtin_amdgcn_mfma_f32_16x16x32_bf16(afl[ks], bh0, a0, 0, 0, 0);
      a1 = __builtin_amdgcn_mfma_f32_16x16x32_bf16(afh[ks], bh1, a1, 0, 0, 0);
      a1 = __builtin_amdgcn_mfma_f32_16x16x32_bf16(afh[ks], bl1, a1, 0, 0, 0);
      a1 = __builtin_amdgcn_mfma_f32_16x16x32_bf16(afl[ks], bh1, a1, 0, 0, 0);
    }
    #pragma unroll
    for (int reg = 0; reg < 4; ++reg) {
      size_t r = (size_t)(r0 + qd*4 + reg);
      float v0 = a0[reg] + b0, v1 = a1[reg] + b0;
      ushort h0 = f2bf(v0), h1 = f2bf(v1);
      p.qkvbuf[r*640 + 256 + c0 + m]      = h0;
      p.qkvbuf[r*640 + 256 + c0 + 16 + m] = h1;
      p.qkvbuf[r*640 + 384 + c0 + m]      = f2bf(v0 - bf2fu(h0));
      p.qkvbuf[r*640 + 384 + c0 + 16 + m] = f2bf(v1 - bf2fu(h1));
    }
  }
  // ---- v (plain bf16) ----
  {
    f4 a0 = zz, a1 = zz;
    #pragma unroll
    for (int ks = 0; ks < 4; ++ks) {
      short8 bh0 = *(const short8*)&p.wv_bf[(c0 + m)*128 + ks*32 + qd*8];
      short8 bh1 = *(const short8*)&p.wv_bf[(c0 + 16 + m)*128 + ks*32 + qd*8];
      a0 = __builtin_amdgcn_mfma_f32_16x16x32_bf16(afh[ks], bh0, a0, 0, 0, 0);
      a1 = __builtin_amdgcn_mfma_f32_16x16x32_bf16(afh[ks], bh1, a1, 0, 0, 0);
    }
    #pragma unroll
    for (int reg = 0; reg < 4; ++reg) {
      size_t r = (size_t)(r0 + qd*4 + reg);
      p.qkvbuf[r*640 + 512 + c0 + m]      = f2bf(a0[reg] + b0);
      p.qkvbuf[r*640 + 512 + c0 + 16 + m] = f2bf(a1[reg] + b0);
    }
  }
}

// ==================================================================
// K2: MFMA attention, split-precision QK^T (3 MFMAs/tile)
// ==================================================================
__global__ __launch_bounds__(256, 2) void attn_kernel(
    const ushort* __restrict__ qkv, const int* __restrict__ maskp,
    ushort* __restrict__ att) {
  __shared__ ushort khb[512*24];     // 24576 B
  __shared__ ushort klb[512*24];     // 24576 B
  __shared__ ushort vT[16*520];      // 16640 B
  __shared__ ushort pbuf[4*640];     //  5120 B
  __shared__ float  smask[512];      //  2048 B   (total 72960)
  int t = threadIdx.x, blk = blockIdx.x;
  int qc = blk & 3, h = (blk >> 2) & 7, b = blk >> 5;
  for (int i = t; i < 512; i += 256) smask[i] = (float)maskp[b*SS + i];
  for (int i = t; i < 1024; i += 256) {
    int s = i >> 1, half = i & 1;
    size_t base = (size_t)(b*SS + s)*640 + h*16 + half*8;
    *(short8*)&khb[s*24 + half*8] = *(const short8*)&qkv[base + 256];
    *(short8*)&klb[s*24 + half*8] = *(const short8*)&qkv[base + 384];
  }
  for (int i = t; i < 2048; i += 256) {
    int s = i >> 2, qu = i & 3;
    short4v v = *(const short4v*)&qkv[(size_t)(b*SS + s)*640 + 512 + h*16 + qu*4];
    #pragma unroll
    for (int j = 0; j < 4; ++j) vT[(qu*4 + j)*520 + s] = (ushort)v[j];
  }
  __syncthreads();
  int wv = t >> 6, lane = t & 63, m = lane & 15, qd = lane >> 4;
  ushort* pb = &pbuf[wv*640];
  f4 zz = {0.f,0.f,0.f,0.f};
  for (int sub = 0; sub < 2; ++sub) {
    int qr0 = qc*128 + sub*64 + wv*16;
    short8 aqh = (short8)0, aql = (short8)0;
    if (qd < 2) {
      size_t base = (size_t)(b*SS + qr0 + m)*640 + h*16 + qd*8;
      aqh = *(const short8*)&qkv[base];
      aql = *(const short8*)&qkv[base + 128];
    }
    f4 oacc = zz;
    float lp0 = 0.f, lp1 = 0.f, lp2 = 0.f, lp3 = 0.f;
    for (int step = 0; step < 16; ++step) {
      int kb = step * 32;
      short8 bh0 = (short8)0, bh1 = (short8)0, bl0 = (short8)0, bl1 = (short8)0;
      if (qd < 2) {
        bh0 = *(const short8*)&khb[(kb + m)*24 + qd*8];
        bh1 = *(const short8*)&khb[(kb + 16 + m)*24 + qd*8];
        bl0 = *(const short8*)&klb[(kb + m)*24 + qd*8];
        bl1 = *(const short8*)&klb[(kb + 16 + m)*24 + qd*8];
      }
      f4 s0 = zz, s1 = zz;
      s0 = __builtin_amdgcn_mfma_f32_16x16x32_bf16(aqh, bh0, s0, 0, 0, 0);
      s0 = __builtin_amdgcn_mfma_f32_16x16x32_bf16(aqh, bl0, s0, 0, 0, 0);
      s0 = __builtin_amdgcn_mfma_f32_16x16x32_bf16(aql, bh0, s0, 0, 0, 0);
      s1 = __builtin_amdgcn_mfma_f32_16x16x32_bf16(aqh, bh1, s1, 0, 0, 0);
      s1 = __builtin_amdgcn_mfma_f32_16x16x32_bf16(aqh, bl1, s1, 0, 0, 0);
      s1 = __builtin_amdgcn_mfma_f32_16x16x32_bf16(aql, bh1, s1, 0, 0, 0);
      float mk0 = smask[kb + m], mk1 = smask[kb + 16 + m];
      #pragma unroll
      for (int reg = 0; reg < 4; ++reg) {
        float e0 = __expf(s0[reg]) * mk0;
        float e1 = __expf(s1[reg]) * mk1;
        ushort p0 = f2bf(e0), p1 = f2bf(e1);
        float er = bf2fu(p0) + bf2fu(p1);     // l consistent with rounded P
        if (reg == 0) lp0 += er; else if (reg == 1) lp1 += er;
        else if (reg == 2) lp2 += er; else lp3 += er;
        pb[(qd*4 + reg)*40 + m]      = p0;
        pb[(qd*4 + reg)*40 + 16 + m] = p1;
      }
      __asm__ volatile("s_waitcnt lgkmcnt(0)" ::: "memory");
      short8 ap = *(const short8*)&pb[m*40 + qd*8];
      short8 bv = *(const short8*)&vT[m*520 + kb + qd*8];
      oacc = __builtin_amdgcn_mfma_f32_16x16x32_bf16(ap, bv, oacc, 0, 0, 0);
    }
    float lp[4] = {lp0, lp1, lp2, lp3};
    #pragma unroll
    for (int reg = 0; reg < 4; ++reg) {
      float l = lp[reg];
      l += __shfl_xor(l, 1); l += __shfl_xor(l, 2);
      l += __shfl_xor(l, 4); l += __shfl_xor(l, 8);
      att[(size_t)(b*SS + qr0 + qd*4 + reg)*128 + h*16 + m] = f2bf(oacc[reg] / l);
    }
  }
}

// ==================================================================
// K3: Wo-proj + residual + LN + FFN1 + FFN2 + residual
// ==================================================================
struct TailParams {
  const ushort* attb; const float* resA;
  const ushort* woT; const ushort* f1w; const ushort* f2w;
  const float* ln_scale; const float* ln_bias; const float* att_bias;
  const float* f1b; const float* f2b; float* out;
};

__global__ __launch_bounds__(256, 2) void tail_kernel(TailParams p) {
  __shared__ float  hres[16*132];
  __shared__ ushort abuf[16*152];
  __shared__ ushort ybuf[16*152];
  int t = threadIdx.x, wv = t >> 6, lane = t & 63;
  int m = lane & 15, qd = lane >> 4, c0 = wv*32;
  int r0 = blockIdx.x * 16;
  float b0 = p.att_bias[0];
  f4 zz = {0.f,0.f,0.f,0.f};

  for (int i = t; i < 256; i += 256) {
    int row = i >> 4, ch = i & 15;
    *(short8*)&abuf[row*152 + ch*8] = *(const short8*)&p.attb[(size_t)(r0 + row)*128 + ch*8];
  }
  __syncthreads();
  {  // Wo projection + residual -> hres
    f4 acc0 = zz, acc1 = zz;
    #pragma unroll
    for (int ks = 0; ks < 4; ++ks) {
      short8 a  = *(const short8*)&abuf[m*152 + ks*32 + qd*8];
      short8 bf0 = *(const short8*)&p.woT[(c0 + m)*128 + ks*32 + qd*8];
      short8 bf1 = *(const short8*)&p.woT[(c0 + 16 + m)*128 + ks*32 + qd*8];
      acc0 = __builtin_amdgcn_mfma_f32_16x16x32_bf16(a, bf0, acc0, 0, 0, 0);
      acc1 = __builtin_amdgcn_mfma_f32_16x16x32_bf16(a, bf1, acc1, 0, 0, 0);
    }
    #pragma unroll
    for (int reg = 0; reg < 4; ++reg) {
      int lr = qd*4 + reg; size_t r = (size_t)(r0 + lr);
      hres[lr*132 + c0 + m]      = acc0[reg] + b0 + p.resA[r*128 + c0 + m];
      hres[lr*132 + c0 + 16 + m] = acc1[reg] + b0 + p.resA[r*128 + c0 + 16 + m];
    }
  }
  __syncthreads();
  {  // LN(hres) -> abuf
    const float* gamma = p.ln_scale + 5*128;
    const float* beta  = p.ln_bias  + 5*128;
    int i = wv*4 + qd;
    float4 xa = *(const float4*)&hres[i*132 + m*8];
    float4 xb = *(const float4*)&hres[i*132 + m*8 + 4];
    float s1 = xa.x+xa.y+xa.z+xa.w + xb.x+xb.y+xb.z+xb.w;
    float s2 = xa.x*xa.x+xa.y*xa.y+xa.z*xa.z+xa.w*xa.w
             + xb.x*xb.x+xb.y*xb.y+xb.z*xb.z+xb.w*xb.w;
    #pragma unroll
    for (int o = 1; o < 16; o <<= 1) { s1 += __shfl_xor(s1, o); s2 += __shfl_xor(s2, o); }
    float mu  = s1 * (1.0f/128.0f);
    float var = s2 * (1.0f/128.0f) - mu*mu;
    float inv = rsqrtf(var + LN_EPS);
    float4 ga = *(const float4*)&gamma[m*8], gb = *(const float4*)&gamma[m*8+4];
    float4 ba = *(const float4*)&beta[m*8],  bb2 = *(const float4*)&beta[m*8+4];
    float n0 = (xa.x-mu)*inv*ga.x + ba.x, n1 = (xa.y-mu)*inv*ga.y + ba.y;
    float n2 = (xa.z-mu)*inv*ga.z + ba.z, n3 = (xa.w-mu)*inv*ga.w + ba.w;
    float n4 = (xb.x-mu)*inv*gb.x + bb2.x, n5 = (xb.y-mu)*inv*gb.y + bb2.y;
    float n6 = (xb.z-mu)*inv*gb.z + bb2.z, n7 = (xb.w-mu)*inv*gb.w + bb2.w;
    *(unsigned*)&abuf[i*152 + m*8    ] = (unsigned)f2bf(n0) | ((unsigned)f2bf(n1) << 16);
    *(unsigned*)&abuf[i*152 + m*8 + 2] = (unsigned)f2bf(n2) | ((unsigned)f2bf(n3) << 16);
    *(unsigned*)&abuf[i*152 + m*8 + 4] = (unsigned)f2bf(n4) | ((unsigned)f2bf(n5) << 16);
    *(unsigned*)&abuf[i*152 + m*8 + 6] = (unsigned)f2bf(n6) | ((unsigned)f2bf(n7) << 16);
  }
  __syncthreads();
  {  // FFN1 + relu -> ybuf
    f4 acc0 = zz, acc1 = zz;
    #pragma unroll
    for (int ks = 0; ks < 4; ++ks) {
      short8 a  = *(const short8*)&abuf[m*152 + ks*32 + qd*8];
      short8 bf0 = *(const short8*)&p.f1w[(c0 + m)*128 + ks*32 + qd*8];
      short8 bf1 = *(const short8*)&p.f1w[(c0 + 16 + m)*128 + ks*32 + qd*8];
      acc0 = __builtin_amdgcn_mfma_f32_16x16x32_bf16(a, bf0, acc0, 0, 0, 0);
      acc1 = __builtin_amdgcn_mfma_f32_16x16x32_bf16(a, bf1, acc1, 0, 0, 0);
    }
    float bv0 = p.f1b[c0 + m], bv1 = p.f1b[c0 + 16 + m];
    #pragma unroll
    for (int reg = 0; reg < 4; ++reg) {
      int lr = qd*4 + reg;
      ybuf[lr*152 + c0 + m]      = f2bf(fmaxf(acc0[reg] + bv0, 0.0f));
      ybuf[lr*152 + c0 + 16 + m] = f2bf(fmaxf(acc1[reg] + bv1, 0.0f));
    }
  }
  __syncthreads();
  {  // FFN2 + residual -> out
    f4 acc0 = zz, acc1 = zz;
    #pragma unroll
    for (int ks = 0; ks < 4; ++ks) {
      short8 a  = *(const short8*)&ybuf[m*152 + ks*32 + qd*8];
      short8 bf0 = *(const short8*)&p.f2w[(c0 + m)*128 + ks*32 + qd*8];
      short8 bf1 = *(const short8*)&p.f2w[(c0 + 16 + m)*128 + ks*32 + qd*8];
      acc0 = __builtin_amdgcn_mfma_f32_16x16x32_bf16(a, bf0, acc0, 0, 0, 0);
      acc1 = __builtin_amdgcn_mfma_f32_16x16x32_bf16(a, bf1, acc1, 0, 0, 0);
    }
    float bv0 = p.f2b[c0 + m], bv1 = p.f2b[c0 + 16 + m];
    #pragma unroll
    for (int reg = 0; reg < 4; ++reg) {
      int lr = qd*4 + reg; size_t r = (size_t)(r0 + lr);
      p.out[r*128 + c0 + m]      = acc0[reg] + bv0 + hres[lr*132 + c0 + m];
      p.out[r*128 + c0 + 16 + m] = acc1[reg] + bv1 + hres[lr*132 + c0 + 16 + m];
    }
  }
}

// ==================================================================
extern "C" void kernel_launch(void* const* d_in, const int* in_sizes, int n_in,
                              void* d_out, int out_size, void* d_ws, size_t ws_size,
                              hipStream_t stream) {
  ushort* wbf    = (ushort*)d_ws;                           // 196608 ushorts
  float*  bufA   = (float*)((char*)d_ws + 393216);          // NN*128 f32
  ushort* qkvbuf = (ushort*)(bufA + (size_t)NN*128);        // NN*640 bf16
  ushort* attbuf = qkvbuf + (size_t)NN*640;                 // NN*128 bf16

  hipLaunchKernelGGL(prep_kernel, dim3(768), dim3(256), 0, stream,
                     (const float*)d_in[6], (const float*)d_in[8], (const float*)d_in[9],
                     (const float*)d_in[10], (const float*)d_in[11], (const float*)d_in[13],
                     (const float*)d_in[15], wbf);

  ConvParams cp;
  cp.x        = (const float*)d_in[0];
  cp.ln_scale = (const float*)d_in[2];
  cp.ln_bias  = (const float*)d_in[3];
  cp.dw_w     = (const float*)d_in[4];
  cp.dw_b     = (const float*)d_in[5];
  cp.pw_b     = (const float*)d_in[7];
  cp.att_bias = (const float*)d_in[12];
  cp.pw_bf    = wbf;
  cp.wq_hi    = wbf + 65536;
  cp.wq_lo    = wbf + 81920;
  cp.wk_hi    = wbf + 98304;
  cp.wk_lo    = wbf + 114688;
  cp.wv_bf    = wbf + 131072;
  cp.bufA = bufA; cp.qkvbuf = qkvbuf;
  hipLaunchKernelGGL(conv_qkv_kernel, dim3(NN/16), dim3(256), 0, stream, cp);

  hipLaunchKernelGGL(attn_kernel, dim3(BB*8*4), dim3(256), 0, stream,
                     qkvbuf, (const int*)d_in[1], attbuf);

  TailParams tp;
  tp.attb = attbuf; tp.resA = bufA;
  tp.woT = wbf + 147456;
  tp.f1w = wbf + 163840;
  tp.f2w = wbf + 180224;
  tp.ln_scale = (const float*)d_in[2];
  tp.ln_bias  = (const float*)d_in[3];
  tp.att_bias = (const float*)d_in[12];
  tp.f1b = (const float*)d_in[14];
  tp.f2b = (const float*)d_in[16];
  tp.out = (float*)d_out;
  hipLaunchKernelGGL(tail_kernel, dim3(NN/16), dim3(256), 0, stream, tp);
}